// Round 15
// baseline (96.097 us; speedup 1.0000x reference)
//
#include <hip/hip_runtime.h>
#include <stdint.h>
#include <stddef.h>

typedef unsigned int u32;
typedef unsigned long long u64;
typedef unsigned short u16;
typedef unsigned char u8;

#define NB 4
#define NLEV 5
#define NCH 72      // A*C = 9*8
#define NREGCH 36   // A*4
#define TOPK 1000
#define NCAND 5000  // NLEV*TOPK
#define NDET 300
#define NBINS 16384       // fallback hist: sigmoid float bits >> 16
#define RNB 4096          // counting-rank buckets (fast path)
#define CAP 8192          // per-(b,level) filtered-candidate buffer
#define FASTCAP 2048      // fast-path key limit (2 keys/thread @ 1024 thr)
#define CHUNK 8192
#define NCHUNK_IMG 50     // 36+9+3+1+1
#define DCH 512           // detect chunk (rank-prefix per NMS round)
#define DW 8              // u64 words per suppression row
#define IMGSZ 512.0f
#define SCORE_TH 0.05f
#define NMS_TH 0.5f
#define BBOX_CLIP_F 4.135166556742356f

__constant__ int c_f[NLEV]    = {64, 32, 16, 8, 4};
__constant__ int c_Nloc[NLEV] = {4096, 1024, 256, 64, 16};
__constant__ int c_lg2[NLEV]  = {12, 10, 8, 6, 4};
// logit prefilter thresholds: ~1400 expected survivors at levels 0-3 (10-sigma
// margins vs both TOPK=1000 and FASTCAP=2048); level 4 unfiltered (1152 total).
__constant__ float c_tau[NLEV] = {2.594f, 2.075f, 1.433f, 0.513f, -1e30f};
// counting-rank bucket shifts: (0x3F800000 - bits(sigmoid(tau))) >> shift < RNB
__constant__ int c_rshift[NLEV] = {10, 10, 11, 12, 18};

// ---- XLA-CPU-style sigmoid: logistic(x) = 0.5 + 0.5*tanh(0.5*x), fast-tanh poly, no FMA ----
__device__ __forceinline__ float xla_tanh_f32(float x) {
  float ax = fabsf(x);
  float xc = fminf(fmaxf(x, -7.90531110763549805f), 7.90531110763549805f);
  float x2 = __fmul_rn(xc, xc);
  float p = -2.76076847742355e-16f;
  p = __fadd_rn(__fmul_rn(x2, p), 2.00018790482477e-13f);
  p = __fadd_rn(__fmul_rn(x2, p), -8.60467152213735e-11f);
  p = __fadd_rn(__fmul_rn(x2, p), 5.12229709037114e-08f);
  p = __fadd_rn(__fmul_rn(x2, p), 1.48572235717979e-05f);
  p = __fadd_rn(__fmul_rn(x2, p), 6.37261928875436e-04f);
  p = __fadd_rn(__fmul_rn(x2, p), 4.89352455891786e-03f);
  float num = __fmul_rn(xc, p);
  float q = 1.19825839466702e-06f;
  q = __fadd_rn(__fmul_rn(x2, q), 1.18534705686654e-04f);
  q = __fadd_rn(__fmul_rn(x2, q), 2.26843463243900e-03f);
  q = __fadd_rn(__fmul_rn(x2, q), 4.89352518554385e-03f);
  float r = __fdiv_rn(num, q);
  return (ax < 0.0004f) ? x : r;
}
__device__ __forceinline__ float sigmoid_ref(float x) {
  return __fadd_rn(0.5f, __fmul_rn(0.5f, xla_tanh_f32(__fmul_rn(0.5f, x))));
}

struct ClsPtrs { const float* p[NLEV]; };
struct LevelPtrs { const float* reg[NLEV]; const float* anc[NLEV]; };

__device__ __forceinline__ void chunk_map(int bid, int& b, int& level, int& chunk) {
  b = bid / NCHUNK_IMG;
  int cid = bid % NCHUNK_IMG;
  if      (cid < 36) { level = 0; chunk = cid; }
  else if (cid < 45) { level = 1; chunk = cid - 36; }
  else if (cid < 48) { level = 2; chunk = cid - 45; }
  else if (cid < 49) { level = 3; chunk = cid - 48; }
  else               { level = 4; chunk = cid - 49; }
}

// exact BoxCoder decode + clip (identical _rn sequence as all passing rounds)
__device__ __forceinline__ float4 decode_box(const LevelPtrs& lp, int b, int lv, u32 e) {
  u32 anc = e >> 3;              // loc*9 + a
  int a = (int)(anc % 9u);
  int loc = (int)(anc / 9u);
  int f = c_f[lv];
  int Nloc = f * f;
  const float* rp = lp.reg[lv];
  const float* ap = lp.anc[lv] + (size_t)anc * 4;
  float r0 = rp[((size_t)b * NREGCH + (a * 4 + 0)) * Nloc + loc];
  float r1 = rp[((size_t)b * NREGCH + (a * 4 + 1)) * Nloc + loc];
  float r2 = rp[((size_t)b * NREGCH + (a * 4 + 2)) * Nloc + loc];
  float r3 = rp[((size_t)b * NREGCH + (a * 4 + 3)) * Nloc + loc];
  float a0 = ap[0], a1 = ap[1], a2 = ap[2], a3 = ap[3];
  float aw = __fsub_rn(a2, a0);
  float ah = __fsub_rn(a3, a1);
  float acx = __fadd_rn(a0, __fmul_rn(0.5f, aw));
  float acy = __fadd_rn(a1, __fmul_rn(0.5f, ah));
  float dw = fminf(r2, BBOX_CLIP_F);
  float dh = fminf(r3, BBOX_CLIP_F);
  float pcx = __fadd_rn(__fmul_rn(r0, aw), acx);
  float pcy = __fadd_rn(__fmul_rn(r1, ah), acy);
  float pw = __fmul_rn(expf(dw), aw);
  float ph = __fmul_rn(expf(dh), ah);
  float hx = __fmul_rn(0.5f, pw);
  float hy = __fmul_rn(0.5f, ph);
  float4 v;
  v.x = fminf(fmaxf(__fsub_rn(pcx, hx), 0.0f), IMGSZ);
  v.y = fminf(fmaxf(__fsub_rn(pcy, hy), 0.0f), IMGSZ);
  v.z = fminf(fmaxf(__fadd_rn(pcx, hx), 0.0f), IMGSZ);
  v.w = fminf(fmaxf(__fadd_rn(pcy, hy), 0.0f), IMGSZ);
  return v;
}

// ---- K1: logit-prefilter; ONE global atomic per block (two-pass ballot scheme) ----
__global__ __launch_bounds__(256)
void k_filter(ClsPtrs cp, u32* __restrict__ selcnt, u64* __restrict__ sel) {
  int b, level, chunk;
  chunk_map(blockIdx.x, b, level, chunk);
  int Nloc = c_Nloc[level], lg2 = c_lg2[level];
  int Nsc = Nloc * NCH;
  int g = b * NLEV + level;
  const float* cls = cp.p[level] + (size_t)b * Nsc;
  float tau = c_tau[level];
  int base = chunk * CHUNK;
  int end = base + CHUNK; if (end > Nsc) end = Nsc;
  int wid = threadIdx.x >> 6, lane = threadIdx.x & 63;
  u64 lowm = (1ull << lane) - 1ull;
  __shared__ u32 wcnt[4];
  __shared__ u32 s_gbase;
  u32 mycnt = 0;
  for (int i = base + threadIdx.x; i < end; i += 256) {
    u64 mk = __ballot((int)(cls[i] > tau));
    mycnt += (u32)__popcll(mk);
  }
  if (lane == 0) wcnt[wid] = mycnt;
  __syncthreads();
  u32 wbase = 0, tot = 0;
  for (int w = 0; w < 4; ++w) { u32 c = wcnt[w]; if (w < wid) wbase += c; tot += c; }
  if (threadIdx.x == 0 && tot) s_gbase = atomicAdd(&selcnt[g], tot);
  __syncthreads();
  if (!tot) return;
  u32 gb = s_gbase;
  u32 run = 0;
  for (int i = base + threadIdx.x; i < end; i += 256) {
    float x = cls[i];
    bool selp = x > tau;                 // monotone sigmoid => logit-space superset filter
    u64 mk = __ballot((int)selp);
    if (selp) {
      u32 pos = gb + wbase + run + (u32)__popcll(mk & lowm);
      if (pos < CAP) {
        u32 bits = __float_as_uint(sigmoid_ref(x));
        int ch = i >> lg2;
        int loc = i & (Nloc - 1);
        u32 e = (u32)(loc * NCH + ch);   // flat score index ((y*f+x)*9+a)*8+c
        sel[(size_t)g * CAP + pos] = ((u64)bits << 32) | (u32)(~e);
      }
    }
    run += (u32)__popcll(mk);
  }
}

// ---- K2: exact top-1000 via LDS counting-rank + fused decode; guarded fast path ----
__global__ __launch_bounds__(1024)
void k_rank(ClsPtrs cp, LevelPtrs lp, const u32* __restrict__ selcnt,
            const u64* __restrict__ sel,
            float* __restrict__ cand_s, u32* __restrict__ cand_t,
            float4* __restrict__ cand_box) {
  __shared__ union {
    struct { u64 keys2[FASTCAP]; u32 hist[RNB]; u32 pfx[RNB]; } f;  // 48 KB
    u32 histfb[NBINS];                                              // 64 KB
    u64 keysfb[CAP];                                                // 64 KB
  } sh;
  __shared__ u32 part[1024];
  __shared__ u32 s_last;
  __shared__ u32 s_cnt;
  __shared__ int s_cut;
  int g = blockIdx.x;
  int b = g / NLEV, l = g % NLEV;
  int Nloc = c_Nloc[l], lg2 = c_lg2[l];
  int Nsc = Nloc * NCH;
  int tid = threadIdx.x;
  int lane = tid & 63;
  u64 lowm = (1ull << lane) - 1ull;
  int obase = b * NCAND + l * TOPK;
  u32 cnt = selcnt[g];
  bool fast = (cnt >= TOPK) && (cnt <= FASTCAP);
  if (fast) {
    u32 m = cnt;
    int shift = c_rshift[l];
    for (int i = tid; i < RNB; i += 1024) { sh.f.hist[i] = 0; }
    if (tid == 0) s_last = 0;
    // my up-to-2 keys straight from global
    u64 k0a = ((u32)tid < m)        ? sel[(size_t)g * CAP + tid]        : 0ULL;
    u64 k0b = ((u32)tid + 1024 < m) ? sel[(size_t)g * CAP + tid + 1024] : 0ULL;
    // bucket: monotone DECREASING in key; clamp handles tails exactly
    auto bkt_of = [&](u64 k) -> int {
      int d = (int)0x3F800000 - (int)(u32)(k >> 32);
      if (d < 0) d = 0;
      int bq = d >> shift;
      return bq > RNB - 1 ? RNB - 1 : bq;
    };
    int ba = bkt_of(k0a), bb = bkt_of(k0b);
    __syncthreads();
    if ((u32)tid < m)        atomicAdd(&sh.f.hist[ba], 1u);
    if ((u32)tid + 1024 < m) atomicAdd(&sh.f.hist[bb], 1u);
    __syncthreads();
    // exclusive prefix scan of hist[RNB] -> pfx
    {
      int t4 = tid * 4;
      u32 h0 = sh.f.hist[t4], h1 = sh.f.hist[t4 + 1], h2 = sh.f.hist[t4 + 2], h3 = sh.f.hist[t4 + 3];
      u32 s4 = h0 + h1 + h2 + h3;
      u32 x = s4;
      for (int d = 1; d < 64; d <<= 1) { u32 y = __shfl_up(x, d); if (lane >= d) x += y; }
      if (lane == 63) part[tid >> 6] = x;
      __syncthreads();
      if (tid == 0) { u32 a = 0; for (int w = 0; w < 16; ++w) { u32 c = part[w]; part[w] = a; a += c; } }
      __syncthreads();
      u32 base2 = part[tid >> 6] + (x - s4);
      sh.f.pfx[t4]     = base2;
      sh.f.pfx[t4 + 1] = base2 + h0;
      sh.f.pfx[t4 + 2] = base2 + h0 + h1;
      sh.f.pfx[t4 + 3] = base2 + h0 + h1 + h2;
    }
    __syncthreads();
    // scatter into bucket-sorted keys2 (pfx becomes running insert ptr)
    if ((u32)tid < m)        { u32 p = atomicAdd(&sh.f.pfx[ba], 1u); sh.f.keys2[p] = k0a; }
    if ((u32)tid + 1024 < m) { u32 p = atomicAdd(&sh.f.pfx[bb], 1u); sh.f.keys2[p] = k0b; }
    __syncthreads();
    // exact rank = bucket_start + within-bucket count of greater keys; emit
    auto emit = [&](u64 k0, int bkt) {
      u32 endq = sh.f.pfx[bkt];            // after scatter: start + size
      u32 startq = endq - sh.f.hist[bkt];
      u32 r = startq;
      for (u32 j = startq; j < endq; ++j) r += (sh.f.keys2[j] > k0) ? 1u : 0u;
      if (r < TOPK) {
        u32 hi = (u32)(k0 >> 32);
        cand_s[obase + r] = __uint_as_float(hi);
        u32 e = ~((u32)k0);
        cand_t[obase + r] = ((u32)l << 19) | (e & 0x7FFFFu);
        cand_box[obase + r] = decode_box(lp, b, l, e);
        if (r == TOPK - 1) s_last = hi;
      }
    };
    if ((u32)tid < m)        emit(k0a, ba);
    if ((u32)tid + 1024 < m) emit(k0b, bb);
    __syncthreads();
    // guard: rank-999 must beat the filter boundary by >64 ulps
    u32 bits_tau = __float_as_uint(sigmoid_ref(c_tau[l]));
    if ((int)cnt != Nsc && !(s_last > bits_tau + 64u)) fast = false;  // block-uniform
  }
  if (fast) return;

  // ---- fallback (never taken for this input; exact for any input) ----
  const float* cls = cp.p[l] + (size_t)b * Nsc;
  __syncthreads();
  for (int i = tid; i < NBINS; i += 1024) sh.histfb[i] = 0;
  if (tid == 0) s_cnt = 0;
  __syncthreads();
  for (int i = tid; i < Nsc; i += 1024) {
    float s = sigmoid_ref(cls[i]);
    atomicAdd(&sh.histfb[__float_as_uint(s) >> 16], 1u);
  }
  __syncthreads();
  { u32 a = 0; for (int j = 0; j < 16; ++j) a += sh.histfb[tid * 16 + j]; part[tid] = a; }
  __syncthreads();
  if (tid == 0) {
    u32 cum = 0; int cut = 0;
    for (int ch = 1023; ch >= 0; --ch) {
      if (cum + part[ch] >= TOPK) {
        u32 cc = cum;
        for (int bin = ch * 16 + 15;; --bin) { cc += sh.histfb[bin]; if (cc >= TOPK) { cut = bin; break; } }
        break;
      }
      cum += part[ch];
    }
    s_cut = cut;
  }
  __syncthreads();
  int cut = s_cut;
  __syncthreads();                 // hist reads done before keys overwrite
  for (int i = tid; i < Nsc; i += 1024) {
    float s = sigmoid_ref(cls[i]);
    u32 bits = __float_as_uint(s);
    bool selp = (int)(bits >> 16) >= cut;
    u64 mk = __ballot((int)selp);
    if (selp) {
      int ldr = __builtin_ctzll(mk);
      u32 pos0 = 0;
      if (lane == ldr) pos0 = atomicAdd(&s_cnt, (u32)__popcll(mk));
      pos0 = (u32)__shfl((int)pos0, ldr);
      u32 pos = pos0 + (u32)__popcll(mk & lowm);
      if (pos < CAP) {
        int ch = i >> lg2;
        int loc = i & (Nloc - 1);
        u32 e = (u32)(loc * NCH + ch);
        sh.keysfb[pos] = ((u64)bits << 32) | (u32)(~e);
      }
    }
  }
  __syncthreads();
  u32 m2 = s_cnt; if (m2 > CAP) m2 = CAP;
  for (u32 i = tid; i < m2; i += 1024) {
    u64 k0 = sh.keysfb[i];
    u32 r = 0;
    #pragma unroll 8
    for (u32 j = 0; j < m2; ++j) r += (sh.keysfb[j] > k0) ? 1u : 0u;
    if (r < TOPK) {
      cand_s[obase + r] = __uint_as_float((u32)(k0 >> 32));
      u32 e = ~((u32)k0);
      cand_t[obase + r] = ((u32)l << 19) | (e & 0x7FFFFu);
      cand_box[obase + r] = decode_box(lp, b, l, e);
    }
  }
  for (u32 r = m2 + tid; r < TOPK; r += 1024) {
    cand_s[obase + r] = -1.0f;
    cand_t[obase + r] = ((u32)l << 19) | r;
    cand_box[obase + r] = make_float4(0.f, 0.f, 0.f, 0.f);
  }
}

// ---- K3: global rank per candidate (wide: 5 blocks/image); scatter rank-ordered
//      offset-box + meta arrays. Valid ranks exact; invalids distinct from back. ----
__global__ __launch_bounds__(1024)
void k_grank(const float* __restrict__ cand_s, const u32* __restrict__ cand_t,
             const float4* __restrict__ cand_box, u32* __restrict__ invCnt,
             float4* __restrict__ rboxOff, u32* __restrict__ rmeta) {
  __shared__ u64 keys[NCAND];   // 40 KB
  int b = blockIdx.y;
  int seg = blockIdx.x;         // level list 0..4
  int tid = threadIdx.x;
  for (int i = tid; i < NCAND; i += 1024) {
    float s = cand_s[b * NCAND + i];
    u32 t = cand_t[b * NCAND + i];
    u32 hi = (s > SCORE_TH) ? __float_as_uint(s) : 0u;
    keys[i] = ((u64)hi << 32) | (u32)(~t);
  }
  __syncthreads();
  if (tid >= TOPK) return;
  int i = seg * TOPK + tid;
  u64 k0 = keys[i];
  u32 hi = (u32)(k0 >> 32);
  u32 t = ~((u32)k0);
  int rank;
  u32 cls = 0;
  if (hi) {
    rank = tid;                               // own list: earlier entries greater
    for (int L = 0; L < NLEV; ++L) {
      if (L == seg) continue;
      const u64* A = keys + L * TOPK;
      int lo = 0, h2 = TOPK;                  // count of A[j] > k0 (monotone)
      while (lo < h2) { int mid = (lo + h2) >> 1; if (A[mid] > k0) lo = mid + 1; else h2 = mid; }
      rank += lo;
    }
    cls = t & 7u;
  } else {
    rank = (NCAND - 1) - (int)atomicAdd(&invCnt[b], 1u);  // distinct, all >= #valid
  }
  float4 v = cand_box[b * NCAND + i];
  float off = __fmul_rn((float)cls, IMGSZ + 1.0f);
  float4 q;
  q.x = __fadd_rn(v.x, off); q.y = __fadd_rn(v.y, off);
  q.z = __fadd_rn(v.z, off); q.w = __fadd_rn(v.w, off);
  rboxOff[b * NCAND + rank] = q;
  rmeta[b * NCAND + rank] = hi ? (((u32)i << 8) | cls) : 0xFFFFFFFFu;
}

// IoU > thresh predicate — identical _rn sequence as reference; div only when inter>0.
// Symmetric in (p,q): max/min commutative, __fadd_rn(pa,qa) commutative.
__device__ __forceinline__ bool iou_gt4(float4 p, float pa, float4 q, float qa) {
  float ltx = fmaxf(p.x, q.x), lty = fmaxf(p.y, q.y);
  float rx  = fminf(p.z, q.z), ry  = fminf(p.w, q.w);
  float ww = fmaxf(__fsub_rn(rx, ltx), 0.0f);
  float hh = fmaxf(__fsub_rn(ry, lty), 0.0f);
  float inter = __fmul_rn(ww, hh);
  bool res = false;
  if (inter > 0.0f) {
    float denom = fmaxf(__fsub_rn(__fadd_rn(pa, qa), inter), 1e-7f);
    res = __fdiv_rn(inter, denom) > NMS_TH;
  }
  return res;
}
__device__ __forceinline__ float area_rn(float4 p) {
  return __fmul_rn(__fsub_rn(p.z, p.x), __fsub_rn(p.w, p.y));
}

// ---- K4: matrix-NMS over rank-prefix chunks + emit ----
// Per chunk of 512 ranks: parallel upper-tri suppression matrix rows[i] (bit j>i
// set iff IoU>0.5 on class-offset boxes; cross-class provably 0), then thread-0
// scalar greedy over NONZERO rows only (suppression is rare), then parallel
// append of kept to the running list. Exact greedy: keep decisions only look
// backward; chunks>=2 pre-test vs kept list (phase A).
__global__ __launch_bounds__(1024)
void k_detect(const float* __restrict__ cand_s, const float4* __restrict__ cand_box,
              const float4* __restrict__ rboxOff, const u32* __restrict__ rmeta,
              float* __restrict__ out) {
  __shared__ float4 sb[DCH];        //  8 KB staged offset boxes
  __shared__ float  sa[DCH];        //  2 KB areas
  __shared__ u32    sm[DCH];        //  2 KB meta
  __shared__ u64    rows[DCH][DW];  // 32 KB suppression matrix
  __shared__ u32    nzmap[DCH / 32];// rows with any bit set
  __shared__ u64    validm[DW], asup[DW], keptm[DW];
  __shared__ float4 kbox[NDET];     // kept offset boxes (phase A for later chunks)
  __shared__ float  karea2[NDET];
  __shared__ u32    kmeta[NDET];    // kept meta in global rank order
  __shared__ u32    s_nk, s_stop;
  int b = blockIdx.x, tid = threadIdx.x;
  int lane = tid & 63;
  if (tid == 0) { s_nk = 0; s_stop = 0; }
  __syncthreads();

  for (int c0 = 0; c0 < NCAND; c0 += DCH) {
    // ---- stage chunk (rank-ordered) ----
    if (tid < DCH) {
      int r = c0 + tid;
      bool ok = r < NCAND;
      float4 q = ok ? rboxOff[b * NCAND + r] : make_float4(0.f, 0.f, 0.f, 0.f);
      sb[tid] = q;
      sa[tid] = area_rn(q);
      sm[tid] = ok ? rmeta[b * NCAND + r] : 0xFFFFFFFFu;
    }
    if (tid < DCH / 32) nzmap[tid] = 0;
    if (tid < DW) asup[tid] = 0;
    __syncthreads();
    int nk0 = (int)s_nk;
    // ---- valid bitmap + phase A vs kept-so-far (chunks >= 2 only) ----
    if (tid < DCH) {
      bool valid = sm[tid] != 0xFFFFFFFFu;
      u64 bv = __ballot((int)valid);
      if (lane == 0) validm[tid >> 6] = bv;
      bool sup = false;
      if (nk0 > 0 && valid) {
        float4 q = sb[tid]; float aq = sa[tid];
        for (int k = 0; k < nk0; ++k)
          sup = sup | iou_gt4(kbox[k], karea2[k], q, aq);
      }
      u64 bs = __ballot((int)sup);
      if (lane == 0) asup[tid >> 6] = bs;
    }
    // ---- suppression matrix: thread t = (row-group rg, col-word cg) ----
    {
      int rg = tid >> 3, cg = tid & 7;      // 128 row-groups x 8 col-words
      int j0 = cg * 64;
      int ibase = rg * 4;
      if (j0 + 64 <= ibase + 1) {           // whole tile is j <= i: all zero
        rows[ibase + 0][cg] = 0; rows[ibase + 1][cg] = 0;
        rows[ibase + 2][cg] = 0; rows[ibase + 3][cg] = 0;
      } else {
        float4 qr0 = sb[ibase + 0], qr1 = sb[ibase + 1], qr2 = sb[ibase + 2], qr3 = sb[ibase + 3];
        float  ar0 = sa[ibase + 0], ar1 = sa[ibase + 1], ar2 = sa[ibase + 2], ar3 = sa[ibase + 3];
        u64 w0 = 0, w1 = 0, w2 = 0, w3 = 0;
        for (int jc = 0; jc < 64; jc += 8) {
          float4 cb0 = sb[j0 + jc + 0], cb1 = sb[j0 + jc + 1], cb2 = sb[j0 + jc + 2], cb3 = sb[j0 + jc + 3];
          float4 cb4 = sb[j0 + jc + 4], cb5 = sb[j0 + jc + 5], cb6 = sb[j0 + jc + 6], cb7 = sb[j0 + jc + 7];
          float  ca0 = sa[j0 + jc + 0], ca1 = sa[j0 + jc + 1], ca2 = sa[j0 + jc + 2], ca3 = sa[j0 + jc + 3];
          float  ca4 = sa[j0 + jc + 4], ca5 = sa[j0 + jc + 5], ca6 = sa[j0 + jc + 6], ca7 = sa[j0 + jc + 7];
          #define TEST(qr, ar, ww, ii)                                              \
            {                                                                       \
              u64 bits = 0;                                                         \
              int j = j0 + jc;                                                      \
              if (j + 0 > (ii) && iou_gt4(qr, ar, cb0, ca0)) bits |= 1ull << (jc + 0); \
              if (j + 1 > (ii) && iou_gt4(qr, ar, cb1, ca1)) bits |= 1ull << (jc + 1); \
              if (j + 2 > (ii) && iou_gt4(qr, ar, cb2, ca2)) bits |= 1ull << (jc + 2); \
              if (j + 3 > (ii) && iou_gt4(qr, ar, cb3, ca3)) bits |= 1ull << (jc + 3); \
              if (j + 4 > (ii) && iou_gt4(qr, ar, cb4, ca4)) bits |= 1ull << (jc + 4); \
              if (j + 5 > (ii) && iou_gt4(qr, ar, cb5, ca5)) bits |= 1ull << (jc + 5); \
              if (j + 6 > (ii) && iou_gt4(qr, ar, cb6, ca6)) bits |= 1ull << (jc + 6); \
              if (j + 7 > (ii) && iou_gt4(qr, ar, cb7, ca7)) bits |= 1ull << (jc + 7); \
              ww |= bits;                                                           \
            }
          TEST(qr0, ar0, w0, ibase + 0)
          TEST(qr1, ar1, w1, ibase + 1)
          TEST(qr2, ar2, w2, ibase + 2)
          TEST(qr3, ar3, w3, ibase + 3)
          #undef TEST
        }
        rows[ibase + 0][cg] = w0; rows[ibase + 1][cg] = w1;
        rows[ibase + 2][cg] = w2; rows[ibase + 3][cg] = w3;
        if (w0) atomicOr(&nzmap[(ibase + 0) >> 5], 1u << ((ibase + 0) & 31));
        if (w1) atomicOr(&nzmap[(ibase + 1) >> 5], 1u << ((ibase + 1) & 31));
        if (w2) atomicOr(&nzmap[(ibase + 2) >> 5], 1u << ((ibase + 2) & 31));
        if (w3) atomicOr(&nzmap[(ibase + 3) >> 5], 1u << ((ibase + 3) & 31));
      }
    }
    __syncthreads();
    // ---- thread-0 scalar greedy scan over nonzero rows (rank order) ----
    if (tid == 0) {
      u64 kw[DW];
      #pragma unroll
      for (int w = 0; w < DW; ++w) kw[w] = validm[w] & ~asup[w];
      for (int mw = 0; mw < DCH / 32; ++mw) {
        u32 nzw = nzmap[mw];
        while (nzw) {
          int bit = __builtin_ctz(nzw); nzw &= nzw - 1;
          int i = mw * 32 + bit;
          if ((kw[i >> 6] >> (i & 63)) & 1ull) {   // i kept => suppress its row
            #pragma unroll
            for (int v = 0; v < DW; ++v) kw[v] &= ~rows[i][v];
          }
        }
      }
      #pragma unroll
      for (int w = 0; w < DW; ++w) keptm[w] = kw[w];
    }
    __syncthreads();
    // ---- append kept to running list in rank order (cap NDET) ----
    if (tid < DCH) {
      int w = tid >> 6;
      u64 kwv = keptm[w];
      bool isk = ((kwv >> (tid & 63)) & 1ull) != 0;
      if (isk) {
        u32 pre = 0;
        for (int v = 0; v < w; ++v) pre += (u32)__popcll(keptm[v]);
        pre += (u32)__popcll(kwv & ((1ull << (tid & 63)) - 1ull));
        u32 pos = (u32)nk0 + pre;
        if (pos < NDET) { kbox[pos] = sb[tid]; karea2[pos] = sa[tid]; kmeta[pos] = sm[tid]; }
      }
    }
    __syncthreads();
    if (tid == 0) {
      u32 add = 0, nvalid = 0;
      #pragma unroll
      for (int w = 0; w < DW; ++w) { add += (u32)__popcll(keptm[w]); nvalid += (u32)__popcll(validm[w]); }
      u32 nn = (u32)nk0 + add; if (nn > NDET) nn = NDET;
      s_nk = nn;
      if (nn >= (u32)NDET || nvalid < (u32)DCH) s_stop = 1;  // enough kept, or invalid tail reached
    }
    __syncthreads();
    if (s_stop) break;
  }

  // ---- emit: boxes [B,300,4] ++ scores [B,300] ++ labels [B,300] ----
  int nf = (int)s_nk;
  for (int k = tid; k < NDET; k += 1024) {
    float bx0 = 0.f, bx1 = 0.f, bx2 = 0.f, bx3 = 0.f, sc = 0.f, lb = -1.0f;
    if (k < nf) {
      u32 m = kmeta[k];
      int io = (int)(m >> 8);
      float4 v = cand_box[b * NCAND + io];
      bx0 = v.x; bx1 = v.y; bx2 = v.z; bx3 = v.w;
      sc = cand_s[b * NCAND + io];
      lb = (float)(m & 0xFFu);
    }
    int idx = b * NDET + k;
    out[(size_t)idx * 4 + 0] = bx0;
    out[(size_t)idx * 4 + 1] = bx1;
    out[(size_t)idx * 4 + 2] = bx2;
    out[(size_t)idx * 4 + 3] = bx3;
    out[NB * NDET * 4 + idx] = sc;
    out[NB * NDET * 5 + idx] = lb;
  }
}

extern "C" void kernel_launch(void* const* d_in, const int* in_sizes, int n_in,
                              void* d_out, int out_size, void* d_ws, size_t ws_size,
                              hipStream_t stream) {
  const float* cls[NLEV]; const float* reg[NLEV]; const float* anc[NLEV];
  bool dict_order = (n_in >= 2) && (in_sizes[1] == 4 * NREGCH * 64 * 64);
  for (int l = 0; l < NLEV; ++l) {
    if (dict_order) {
      cls[l] = (const float*)d_in[3 * l + 0];
      reg[l] = (const float*)d_in[3 * l + 1];
      anc[l] = (const float*)d_in[3 * l + 2];
    } else {
      cls[l] = (const float*)d_in[l];
      reg[l] = (const float*)d_in[NLEV + l];
      anc[l] = (const float*)d_in[2 * NLEV + l];
    }
  }

  char* ws = (char*)d_ws;
  size_t off = 0;
  auto alloc = [&](size_t bytes) -> void* {
    void* p = ws + off;
    off = (off + bytes + 255) & ~(size_t)255;
    return p;
  };
  u32*    ctrs     = (u32*)   alloc(24 * 4);   // [0,20): selcnt, [20,24): invCnt
  u64*    sel      = (u64*)   alloc(20ULL * CAP * 8);
  float*  cand_s   = (float*) alloc((size_t)NB * NCAND * 4);
  u32*    cand_t   = (u32*)   alloc((size_t)NB * NCAND * 4);
  float4* cand_box = (float4*)alloc((size_t)NB * NCAND * 16);
  float4* rboxOff  = (float4*)alloc((size_t)NB * NCAND * 16);
  u32*    rmeta    = (u32*)   alloc((size_t)NB * NCAND * 4);
  (void)ws_size; (void)out_size;

  u32* selcnt = ctrs;
  u32* invCnt = ctrs + 20;
  hipMemsetAsync(ctrs, 0, 24 * 4, stream);

  ClsPtrs cp;
  for (int l = 0; l < NLEV; ++l) cp.p[l] = cls[l];
  LevelPtrs lp;
  for (int l = 0; l < NLEV; ++l) { lp.reg[l] = reg[l]; lp.anc[l] = anc[l]; }

  k_filter<<<NB * NCHUNK_IMG, 256, 0, stream>>>(cp, selcnt, sel);
  k_rank<<<NB * NLEV, 1024, 0, stream>>>(cp, lp, selcnt, sel, cand_s, cand_t, cand_box);
  k_grank<<<dim3(NLEV, NB), 1024, 0, stream>>>(cand_s, cand_t, cand_box, invCnt, rboxOff, rmeta);
  k_detect<<<NB, 1024, 0, stream>>>(cand_s, cand_box, rboxOff, rmeta, (float*)d_out);
}

// Round 16
// 63.792 us; speedup vs baseline: 1.5064x; 1.5064x over previous
//
#include <hip/hip_runtime.h>
#include <stdint.h>
#include <stddef.h>

typedef unsigned int u32;
typedef unsigned long long u64;
typedef unsigned short u16;
typedef unsigned char u8;

#define NB 4
#define NLEV 5
#define NCH 72      // A*C = 9*8
#define NREGCH 36   // A*4
#define TOPK 1000
#define NCAND 5000  // NLEV*TOPK
#define NDET 300
#define NBINS 16384       // fallback hist: sigmoid float bits >> 16
#define RNB 4096          // counting-rank buckets (fast path)
#define CAP 8192          // per-(b,level) filtered-candidate buffer
#define FASTCAP 2048      // fast-path key limit (2 keys/thread @ 1024 thr)
#define CHUNK 8192
#define NCHUNK_IMG 50     // 36+9+3+1+1
#define DCH 512           // NMS rank-prefix chunk
#define DW 8              // u64 words per suppression row
#define IMGSZ 512.0f
#define SCORE_TH 0.05f
#define NMS_TH 0.5f
#define BBOX_CLIP_F 4.135166556742356f

__constant__ int c_f[NLEV]    = {64, 32, 16, 8, 4};
__constant__ int c_Nloc[NLEV] = {4096, 1024, 256, 64, 16};
__constant__ int c_lg2[NLEV]  = {12, 10, 8, 6, 4};
// logit prefilter thresholds: ~1400 expected survivors at levels 0-3 (10-sigma
// margins vs both TOPK=1000 and FASTCAP=2048); level 4 unfiltered (1152 total).
__constant__ float c_tau[NLEV] = {2.594f, 2.075f, 1.433f, 0.513f, -1e30f};
// counting-rank bucket shifts: (0x3F800000 - bits(sigmoid(tau))) >> shift < RNB
__constant__ int c_rshift[NLEV] = {10, 10, 11, 12, 18};

// ---- XLA-CPU-style sigmoid: logistic(x) = 0.5 + 0.5*tanh(0.5*x), fast-tanh poly, no FMA ----
__device__ __forceinline__ float xla_tanh_f32(float x) {
  float ax = fabsf(x);
  float xc = fminf(fmaxf(x, -7.90531110763549805f), 7.90531110763549805f);
  float x2 = __fmul_rn(xc, xc);
  float p = -2.76076847742355e-16f;
  p = __fadd_rn(__fmul_rn(x2, p), 2.00018790482477e-13f);
  p = __fadd_rn(__fmul_rn(x2, p), -8.60467152213735e-11f);
  p = __fadd_rn(__fmul_rn(x2, p), 5.12229709037114e-08f);
  p = __fadd_rn(__fmul_rn(x2, p), 1.48572235717979e-05f);
  p = __fadd_rn(__fmul_rn(x2, p), 6.37261928875436e-04f);
  p = __fadd_rn(__fmul_rn(x2, p), 4.89352455891786e-03f);
  float num = __fmul_rn(xc, p);
  float q = 1.19825839466702e-06f;
  q = __fadd_rn(__fmul_rn(x2, q), 1.18534705686654e-04f);
  q = __fadd_rn(__fmul_rn(x2, q), 2.26843463243900e-03f);
  q = __fadd_rn(__fmul_rn(x2, q), 4.89352518554385e-03f);
  float r = __fdiv_rn(num, q);
  return (ax < 0.0004f) ? x : r;
}
__device__ __forceinline__ float sigmoid_ref(float x) {
  return __fadd_rn(0.5f, __fmul_rn(0.5f, xla_tanh_f32(__fmul_rn(0.5f, x))));
}

struct ClsPtrs { const float* p[NLEV]; };
struct LevelPtrs { const float* reg[NLEV]; const float* anc[NLEV]; };

__device__ __forceinline__ void chunk_map(int bid, int& b, int& level, int& chunk) {
  b = bid / NCHUNK_IMG;
  int cid = bid % NCHUNK_IMG;
  if      (cid < 36) { level = 0; chunk = cid; }
  else if (cid < 45) { level = 1; chunk = cid - 36; }
  else if (cid < 48) { level = 2; chunk = cid - 45; }
  else if (cid < 49) { level = 3; chunk = cid - 48; }
  else               { level = 4; chunk = cid - 49; }
}

// exact BoxCoder decode + clip (identical _rn sequence as all passing rounds)
__device__ __forceinline__ float4 decode_box(const LevelPtrs& lp, int b, int lv, u32 e) {
  u32 anc = e >> 3;              // loc*9 + a
  int a = (int)(anc % 9u);
  int loc = (int)(anc / 9u);
  int f = c_f[lv];
  int Nloc = f * f;
  const float* rp = lp.reg[lv];
  const float* ap = lp.anc[lv] + (size_t)anc * 4;
  float r0 = rp[((size_t)b * NREGCH + (a * 4 + 0)) * Nloc + loc];
  float r1 = rp[((size_t)b * NREGCH + (a * 4 + 1)) * Nloc + loc];
  float r2 = rp[((size_t)b * NREGCH + (a * 4 + 2)) * Nloc + loc];
  float r3 = rp[((size_t)b * NREGCH + (a * 4 + 3)) * Nloc + loc];
  float a0 = ap[0], a1 = ap[1], a2 = ap[2], a3 = ap[3];
  float aw = __fsub_rn(a2, a0);
  float ah = __fsub_rn(a3, a1);
  float acx = __fadd_rn(a0, __fmul_rn(0.5f, aw));
  float acy = __fadd_rn(a1, __fmul_rn(0.5f, ah));
  float dw = fminf(r2, BBOX_CLIP_F);
  float dh = fminf(r3, BBOX_CLIP_F);
  float pcx = __fadd_rn(__fmul_rn(r0, aw), acx);
  float pcy = __fadd_rn(__fmul_rn(r1, ah), acy);
  float pw = __fmul_rn(expf(dw), aw);
  float ph = __fmul_rn(expf(dh), ah);
  float hx = __fmul_rn(0.5f, pw);
  float hy = __fmul_rn(0.5f, ph);
  float4 v;
  v.x = fminf(fmaxf(__fsub_rn(pcx, hx), 0.0f), IMGSZ);
  v.y = fminf(fmaxf(__fsub_rn(pcy, hy), 0.0f), IMGSZ);
  v.z = fminf(fmaxf(__fadd_rn(pcx, hx), 0.0f), IMGSZ);
  v.w = fminf(fmaxf(__fadd_rn(pcy, hy), 0.0f), IMGSZ);
  return v;
}

// ---- K1: logit-prefilter; ONE global atomic per block (two-pass ballot scheme) ----
__global__ __launch_bounds__(256)
void k_filter(ClsPtrs cp, u32* __restrict__ selcnt, u64* __restrict__ sel) {
  int b, level, chunk;
  chunk_map(blockIdx.x, b, level, chunk);
  int Nloc = c_Nloc[level], lg2 = c_lg2[level];
  int Nsc = Nloc * NCH;
  int g = b * NLEV + level;
  const float* cls = cp.p[level] + (size_t)b * Nsc;
  float tau = c_tau[level];
  int base = chunk * CHUNK;
  int end = base + CHUNK; if (end > Nsc) end = Nsc;
  int wid = threadIdx.x >> 6, lane = threadIdx.x & 63;
  u64 lowm = (1ull << lane) - 1ull;
  __shared__ u32 wcnt[4];
  __shared__ u32 s_gbase;
  u32 mycnt = 0;
  for (int i = base + threadIdx.x; i < end; i += 256) {
    u64 mk = __ballot((int)(cls[i] > tau));
    mycnt += (u32)__popcll(mk);
  }
  if (lane == 0) wcnt[wid] = mycnt;
  __syncthreads();
  u32 wbase = 0, tot = 0;
  for (int w = 0; w < 4; ++w) { u32 c = wcnt[w]; if (w < wid) wbase += c; tot += c; }
  if (threadIdx.x == 0 && tot) s_gbase = atomicAdd(&selcnt[g], tot);
  __syncthreads();
  if (!tot) return;
  u32 gb = s_gbase;
  u32 run = 0;
  for (int i = base + threadIdx.x; i < end; i += 256) {
    float x = cls[i];
    bool selp = x > tau;                 // monotone sigmoid => logit-space superset filter
    u64 mk = __ballot((int)selp);
    if (selp) {
      u32 pos = gb + wbase + run + (u32)__popcll(mk & lowm);
      if (pos < CAP) {
        u32 bits = __float_as_uint(sigmoid_ref(x));
        int ch = i >> lg2;
        int loc = i & (Nloc - 1);
        u32 e = (u32)(loc * NCH + ch);   // flat score index ((y*f+x)*9+a)*8+c
        sel[(size_t)g * CAP + pos] = ((u64)bits << 32) | (u32)(~e);
      }
    }
    run += (u32)__popcll(mk);
  }
}

// ---- K2: exact top-1000 via LDS counting-rank + fused decode; guarded fast path ----
__global__ __launch_bounds__(1024)
void k_rank(ClsPtrs cp, LevelPtrs lp, const u32* __restrict__ selcnt,
            const u64* __restrict__ sel,
            float* __restrict__ cand_s, u32* __restrict__ cand_t,
            float4* __restrict__ cand_box) {
  __shared__ union {
    struct { u64 keys2[FASTCAP]; u32 hist[RNB]; u32 pfx[RNB]; } f;  // 48 KB
    u32 histfb[NBINS];                                              // 64 KB
    u64 keysfb[CAP];                                                // 64 KB
  } sh;
  __shared__ u32 part[1024];
  __shared__ u32 s_last;
  __shared__ u32 s_cnt;
  __shared__ int s_cut;
  int g = blockIdx.x;
  int b = g / NLEV, l = g % NLEV;
  int Nloc = c_Nloc[l], lg2 = c_lg2[l];
  int Nsc = Nloc * NCH;
  int tid = threadIdx.x;
  int lane = tid & 63;
  u64 lowm = (1ull << lane) - 1ull;
  int obase = b * NCAND + l * TOPK;
  u32 cnt = selcnt[g];
  bool fast = (cnt >= TOPK) && (cnt <= FASTCAP);
  if (fast) {
    u32 m = cnt;
    int shift = c_rshift[l];
    for (int i = tid; i < RNB; i += 1024) { sh.f.hist[i] = 0; }
    if (tid == 0) s_last = 0;
    // my up-to-2 keys straight from global
    u64 k0a = ((u32)tid < m)        ? sel[(size_t)g * CAP + tid]        : 0ULL;
    u64 k0b = ((u32)tid + 1024 < m) ? sel[(size_t)g * CAP + tid + 1024] : 0ULL;
    // bucket: monotone DECREASING in key; clamp handles tails exactly
    auto bkt_of = [&](u64 k) -> int {
      int d = (int)0x3F800000 - (int)(u32)(k >> 32);
      if (d < 0) d = 0;
      int bq = d >> shift;
      return bq > RNB - 1 ? RNB - 1 : bq;
    };
    int ba = bkt_of(k0a), bb = bkt_of(k0b);
    __syncthreads();
    if ((u32)tid < m)        atomicAdd(&sh.f.hist[ba], 1u);
    if ((u32)tid + 1024 < m) atomicAdd(&sh.f.hist[bb], 1u);
    __syncthreads();
    // exclusive prefix scan of hist[RNB] -> pfx
    {
      int t4 = tid * 4;
      u32 h0 = sh.f.hist[t4], h1 = sh.f.hist[t4 + 1], h2 = sh.f.hist[t4 + 2], h3 = sh.f.hist[t4 + 3];
      u32 s4 = h0 + h1 + h2 + h3;
      u32 x = s4;
      for (int d = 1; d < 64; d <<= 1) { u32 y = __shfl_up(x, d); if (lane >= d) x += y; }
      if (lane == 63) part[tid >> 6] = x;
      __syncthreads();
      if (tid == 0) { u32 a = 0; for (int w = 0; w < 16; ++w) { u32 c = part[w]; part[w] = a; a += c; } }
      __syncthreads();
      u32 base2 = part[tid >> 6] + (x - s4);
      sh.f.pfx[t4]     = base2;
      sh.f.pfx[t4 + 1] = base2 + h0;
      sh.f.pfx[t4 + 2] = base2 + h0 + h1;
      sh.f.pfx[t4 + 3] = base2 + h0 + h1 + h2;
    }
    __syncthreads();
    // scatter into bucket-sorted keys2 (pfx becomes running insert ptr)
    if ((u32)tid < m)        { u32 p = atomicAdd(&sh.f.pfx[ba], 1u); sh.f.keys2[p] = k0a; }
    if ((u32)tid + 1024 < m) { u32 p = atomicAdd(&sh.f.pfx[bb], 1u); sh.f.keys2[p] = k0b; }
    __syncthreads();
    // exact rank = bucket_start + within-bucket count of greater keys; emit
    auto emit = [&](u64 k0, int bkt) {
      u32 endq = sh.f.pfx[bkt];            // after scatter: start + size
      u32 startq = endq - sh.f.hist[bkt];
      u32 r = startq;
      for (u32 j = startq; j < endq; ++j) r += (sh.f.keys2[j] > k0) ? 1u : 0u;
      if (r < TOPK) {
        u32 hi = (u32)(k0 >> 32);
        cand_s[obase + r] = __uint_as_float(hi);
        u32 e = ~((u32)k0);
        cand_t[obase + r] = ((u32)l << 19) | (e & 0x7FFFFu);
        cand_box[obase + r] = decode_box(lp, b, l, e);
        if (r == TOPK - 1) s_last = hi;
      }
    };
    if ((u32)tid < m)        emit(k0a, ba);
    if ((u32)tid + 1024 < m) emit(k0b, bb);
    __syncthreads();
    // guard: rank-999 must beat the filter boundary by >64 ulps
    u32 bits_tau = __float_as_uint(sigmoid_ref(c_tau[l]));
    if ((int)cnt != Nsc && !(s_last > bits_tau + 64u)) fast = false;  // block-uniform
  }
  if (fast) return;

  // ---- fallback (never taken for this input; exact for any input) ----
  const float* cls = cp.p[l] + (size_t)b * Nsc;
  __syncthreads();
  for (int i = tid; i < NBINS; i += 1024) sh.histfb[i] = 0;
  if (tid == 0) s_cnt = 0;
  __syncthreads();
  for (int i = tid; i < Nsc; i += 1024) {
    float s = sigmoid_ref(cls[i]);
    atomicAdd(&sh.histfb[__float_as_uint(s) >> 16], 1u);
  }
  __syncthreads();
  { u32 a = 0; for (int j = 0; j < 16; ++j) a += sh.histfb[tid * 16 + j]; part[tid] = a; }
  __syncthreads();
  if (tid == 0) {
    u32 cum = 0; int cut = 0;
    for (int ch = 1023; ch >= 0; --ch) {
      if (cum + part[ch] >= TOPK) {
        u32 cc = cum;
        for (int bin = ch * 16 + 15;; --bin) { cc += sh.histfb[bin]; if (cc >= TOPK) { cut = bin; break; } }
        break;
      }
      cum += part[ch];
    }
    s_cut = cut;
  }
  __syncthreads();
  int cut = s_cut;
  __syncthreads();                 // hist reads done before keys overwrite
  for (int i = tid; i < Nsc; i += 1024) {
    float s = sigmoid_ref(cls[i]);
    u32 bits = __float_as_uint(s);
    bool selp = (int)(bits >> 16) >= cut;
    u64 mk = __ballot((int)selp);
    if (selp) {
      int ldr = __builtin_ctzll(mk);
      u32 pos0 = 0;
      if (lane == ldr) pos0 = atomicAdd(&s_cnt, (u32)__popcll(mk));
      pos0 = (u32)__shfl((int)pos0, ldr);
      u32 pos = pos0 + (u32)__popcll(mk & lowm);
      if (pos < CAP) {
        int ch = i >> lg2;
        int loc = i & (Nloc - 1);
        u32 e = (u32)(loc * NCH + ch);
        sh.keysfb[pos] = ((u64)bits << 32) | (u32)(~e);
      }
    }
  }
  __syncthreads();
  u32 m2 = s_cnt; if (m2 > CAP) m2 = CAP;
  for (u32 i = tid; i < m2; i += 1024) {
    u64 k0 = sh.keysfb[i];
    u32 r = 0;
    #pragma unroll 8
    for (u32 j = 0; j < m2; ++j) r += (sh.keysfb[j] > k0) ? 1u : 0u;
    if (r < TOPK) {
      cand_s[obase + r] = __uint_as_float((u32)(k0 >> 32));
      u32 e = ~((u32)k0);
      cand_t[obase + r] = ((u32)l << 19) | (e & 0x7FFFFu);
      cand_box[obase + r] = decode_box(lp, b, l, e);
    }
  }
  for (u32 r = m2 + tid; r < TOPK; r += 1024) {
    cand_s[obase + r] = -1.0f;
    cand_t[obase + r] = ((u32)l << 19) | r;
    cand_box[obase + r] = make_float4(0.f, 0.f, 0.f, 0.f);
  }
}

// ---- K3: global rank per candidate (wide: 5 blocks/image); scatter rank-ordered
//      offset-box + meta arrays. Valid ranks exact; invalids distinct from back. ----
__global__ __launch_bounds__(1024)
void k_grank(const float* __restrict__ cand_s, const u32* __restrict__ cand_t,
             const float4* __restrict__ cand_box, u32* __restrict__ invCnt,
             float4* __restrict__ rboxOff, u32* __restrict__ rmeta) {
  __shared__ u64 keys[NCAND];   // 40 KB
  int b = blockIdx.y;
  int seg = blockIdx.x;         // level list 0..4
  int tid = threadIdx.x;
  for (int i = tid; i < NCAND; i += 1024) {
    float s = cand_s[b * NCAND + i];
    u32 t = cand_t[b * NCAND + i];
    u32 hi = (s > SCORE_TH) ? __float_as_uint(s) : 0u;
    keys[i] = ((u64)hi << 32) | (u32)(~t);
  }
  __syncthreads();
  if (tid >= TOPK) return;
  int i = seg * TOPK + tid;
  u64 k0 = keys[i];
  u32 hi = (u32)(k0 >> 32);
  u32 t = ~((u32)k0);
  int rank;
  u32 cls = 0;
  if (hi) {
    rank = tid;                               // own list: earlier entries greater
    for (int L = 0; L < NLEV; ++L) {
      if (L == seg) continue;
      const u64* A = keys + L * TOPK;
      int lo = 0, h2 = TOPK;                  // count of A[j] > k0 (monotone)
      while (lo < h2) { int mid = (lo + h2) >> 1; if (A[mid] > k0) lo = mid + 1; else h2 = mid; }
      rank += lo;
    }
    cls = t & 7u;
  } else {
    rank = (NCAND - 1) - (int)atomicAdd(&invCnt[b], 1u);  // distinct, all >= #valid
  }
  float4 v = cand_box[b * NCAND + i];
  float off = __fmul_rn((float)cls, IMGSZ + 1.0f);
  float4 q;
  q.x = __fadd_rn(v.x, off); q.y = __fadd_rn(v.y, off);
  q.z = __fadd_rn(v.z, off); q.w = __fadd_rn(v.w, off);
  rboxOff[b * NCAND + rank] = q;
  rmeta[b * NCAND + rank] = hi ? (((u32)i << 8) | cls) : 0xFFFFFFFFu;
}

// IoU > thresh predicate — identical _rn sequence as reference; div only when inter>0.
__device__ __forceinline__ bool iou_gt4(float4 p, float pa, float4 q, float qa) {
  float ltx = fmaxf(p.x, q.x), lty = fmaxf(p.y, q.y);
  float rx  = fminf(p.z, q.z), ry  = fminf(p.w, q.w);
  float ww = fmaxf(__fsub_rn(rx, ltx), 0.0f);
  float hh = fmaxf(__fsub_rn(ry, lty), 0.0f);
  float inter = __fmul_rn(ww, hh);
  bool res = false;
  if (inter > 0.0f) {
    float denom = fmaxf(__fsub_rn(__fadd_rn(pa, qa), inter), 1e-7f);
    res = __fdiv_rn(inter, denom) > NMS_TH;
  }
  return res;
}
__device__ __forceinline__ float area_rn(float4 p) {
  return __fmul_rn(__fsub_rn(p.z, p.x), __fsub_rn(p.w, p.y));
}

// ---- K4: wide suppression-matrix build over the 512-rank prefix ----
// 8 row-blocks x NB images. Wave handles one column-word at a time: sb[] column
// reads are wave-uniform (broadcast, no bank conflicts). Tiles fully above the
// diagonal are unguarded; only the diagonal word carries j>r predicates.
__global__ __launch_bounds__(256)
void k_mask(const float4* __restrict__ rboxOff, u64* __restrict__ rowsG) {
  __shared__ float4 sb[DCH];   // 8 KB offset boxes
  __shared__ float  sa[DCH];   // 2 KB areas
  int b = blockIdx.y, rb = blockIdx.x;   // row-block: rows rb*64 .. rb*64+63
  int tid = threadIdx.x;
  for (int i = tid; i < DCH; i += 256) {
    float4 q = rboxOff[b * NCAND + i];
    sb[i] = q; sa[i] = area_rn(q);
  }
  __syncthreads();
  int lane = tid & 63, wv = tid >> 6;
  int r = rb * 64 + lane;
  float4 qr = sb[r]; float ar = sa[r];
  u64* rowp = rowsG + ((size_t)b * DCH + r) * DW;
  // zero words fully below diagonal
  for (int w = wv; w < rb; w += 4) rowp[w] = 0;
  // compute words w >= rb (wave-uniform w)
  for (int w = rb + wv; w < DW; w += 4) {
    u64 bits = 0;
    int j0 = w * 64;
    if (w > rb) {
      #pragma unroll 4
      for (int jc = 0; jc < 64; ++jc)
        if (iou_gt4(qr, ar, sb[j0 + jc], sa[j0 + jc])) bits |= 1ull << jc;
    } else {                                // diagonal word: guard j > r
      #pragma unroll 4
      for (int jc = 0; jc < 64; ++jc) {
        int j = j0 + jc;
        if (j > r && iou_gt4(qr, ar, sb[j], sa[j])) bits |= 1ull << jc;
      }
    }
    rowp[w] = bits;
  }
}

// ---- K5: scalar greedy over precomputed matrix + append + emit; exact fallback ----
__global__ __launch_bounds__(1024)
void k_detect(const float* __restrict__ cand_s, const float4* __restrict__ cand_box,
              const float4* __restrict__ rboxOff, const u32* __restrict__ rmeta,
              const u64* __restrict__ rowsG, float* __restrict__ out) {
  __shared__ u64 rows[DCH][DW];     // 32 KB
  __shared__ u32 sm[DCH];           //  2 KB
  __shared__ u32 nzmap[DCH / 32];
  __shared__ u64 validm[DW], keptm[DW];
  __shared__ float4 kbox[NDET];     // kept offset boxes (fallback phase A)
  __shared__ float  karea2[NDET];
  __shared__ u32    kmeta[NDET];
  __shared__ float4 cbox[64];
  __shared__ float  carea[64];
  __shared__ u64    supsh[16];
  __shared__ u32 s_nk, s_stop;
  int b = blockIdx.x, tid = threadIdx.x;
  int lane = tid & 63, wid = tid >> 6;
  if (tid < DCH / 32) nzmap[tid] = 0;
  if (tid == 0) { s_nk = 0; s_stop = 0; }
  __syncthreads();
  // load matrix (coalesced) + nz bits + meta
  for (int k = tid; k < DCH * DW; k += 1024) {
    u64 v = rowsG[(size_t)b * DCH * DW + k];
    ((u64*)rows)[k] = v;
    if (v) atomicOr(&nzmap[(k / DW) >> 5], 1u << ((k / DW) & 31));
  }
  if (tid < DCH) sm[tid] = rmeta[b * NCAND + tid];
  __syncthreads();
  if (tid < DCH) {
    u64 bv = __ballot((int)(sm[tid] != 0xFFFFFFFFu));
    if (lane == 0) validm[tid >> 6] = bv;
  }
  __syncthreads();
  // scalar greedy over nonzero rows only (rank order); suppression is rare
  if (tid == 0) {
    u64 kw[DW];
    #pragma unroll
    for (int w = 0; w < DW; ++w) kw[w] = validm[w];
    for (int mw = 0; mw < DCH / 32; ++mw) {
      u32 nzw = nzmap[mw];
      while (nzw) {
        int bit = __builtin_ctz(nzw); nzw &= nzw - 1;
        int i = mw * 32 + bit;
        if ((kw[i >> 6] >> (i & 63)) & 1ull) {
          #pragma unroll
          for (int v = 0; v < DW; ++v) kw[v] &= ~rows[i][v];
        }
      }
    }
    #pragma unroll
    for (int w = 0; w < DW; ++w) keptm[w] = kw[w];
  }
  __syncthreads();
  // append kept (rank order, cap NDET); gather kept boxes for fallback
  if (tid < DCH) {
    int w = tid >> 6;
    u64 kwv = keptm[w];
    if ((kwv >> (tid & 63)) & 1ull) {
      u32 pre = 0;
      for (int v = 0; v < w; ++v) pre += (u32)__popcll(keptm[v]);
      pre += (u32)__popcll(kwv & ((1ull << (tid & 63)) - 1ull));
      if (pre < NDET) {
        float4 q = rboxOff[b * NCAND + tid];
        kbox[pre] = q; karea2[pre] = area_rn(q); kmeta[pre] = sm[tid];
      }
    }
  }
  __syncthreads();
  if (tid == 0) {
    u32 add = 0, nvalid = 0;
    #pragma unroll
    for (int w = 0; w < DW; ++w) { add += (u32)__popcll(keptm[w]); nvalid += (u32)__popcll(validm[w]); }
    u32 nn = add; if (nn > NDET) nn = NDET;
    s_nk = nn;
    if (nn >= (u32)NDET || nvalid < (u32)DCH) s_stop = 1;
  }
  __syncthreads();

  // ---- fallback for ranks >= DCH (rare; exact greedy, single combined kept list:
  //      cross-class IoU provably 0, so one list == per-class lists) ----
  int n = (int)s_nk;
  for (int base = DCH; base < NCAND && !s_stop; base += 64) {
    int ci = base + lane;
    u32 meta = (ci < NCAND) ? rmeta[b * NCAND + ci] : 0xFFFFFFFFu;
    bool valid = meta != 0xFFFFFFFFu;
    float4 q = (ci < NCAND) ? rboxOff[b * NCAND + ci] : make_float4(0.f, 0.f, 0.f, 0.f);
    float aq = area_rn(q);
    if (wid == 0) { cbox[lane] = q; carea[lane] = aq; }
    bool sup = false;
    if (valid) for (int k = wid; k < n; k += 16) sup = sup | iou_gt4(kbox[k], karea2[k], q, aq);
    u64 bal = __ballot((int)sup);
    if (lane == 0) supsh[wid] = bal;
    __syncthreads();
    if (wid == 0) {
      u64 supm = 0;
      for (int w = 0; w < 16; ++w) supm |= supsh[w];
      u64 vm = __ballot((int)valid);
      u64 pending = vm & ~supm;
      u64 row = 0;
      if ((pending >> lane) & 1ull) {
        u64 mine = pending & ~((2ull << lane) - 1ull);
        while (mine) {
          int j = __builtin_ctzll(mine); mine &= mine - 1ull;
          if (iou_gt4(q, aq, cbox[j], carea[j])) row |= (1ull << j);
        }
      }
      __shared__ u64 rowsh2[64];
      rowsh2[lane] = row;
      u64 nz = __ballot((int)(row != 0ull));
      bool done = false;
      u64 rem = pending;
      while (rem) {
        int r = __builtin_ctzll(rem); rem &= rem - 1ull;
        if (lane == r) { kmeta[n] = meta; kbox[n] = q; karea2[n] = aq; }
        ++n;
        if (n == NDET) { done = true; break; }
        if ((nz >> r) & 1ull) rem &= ~rowsh2[r];
      }
      if (__any((int)(!valid))) done = true;
      if (lane == 0) { s_nk = (u32)n; s_stop = done ? 1u : 0u; }
    }
    __syncthreads();
    n = (int)s_nk;
  }

  // ---- emit: boxes [B,300,4] ++ scores [B,300] ++ labels [B,300] ----
  int nf = (int)s_nk;
  for (int k = tid; k < NDET; k += 1024) {
    float bx0 = 0.f, bx1 = 0.f, bx2 = 0.f, bx3 = 0.f, sc = 0.f, lb = -1.0f;
    if (k < nf) {
      u32 m = kmeta[k];
      int io = (int)(m >> 8);
      float4 v = cand_box[b * NCAND + io];
      bx0 = v.x; bx1 = v.y; bx2 = v.z; bx3 = v.w;
      sc = cand_s[b * NCAND + io];
      lb = (float)(m & 0xFFu);
    }
    int idx = b * NDET + k;
    out[(size_t)idx * 4 + 0] = bx0;
    out[(size_t)idx * 4 + 1] = bx1;
    out[(size_t)idx * 4 + 2] = bx2;
    out[(size_t)idx * 4 + 3] = bx3;
    out[NB * NDET * 4 + idx] = sc;
    out[NB * NDET * 5 + idx] = lb;
  }
}

extern "C" void kernel_launch(void* const* d_in, const int* in_sizes, int n_in,
                              void* d_out, int out_size, void* d_ws, size_t ws_size,
                              hipStream_t stream) {
  const float* cls[NLEV]; const float* reg[NLEV]; const float* anc[NLEV];
  bool dict_order = (n_in >= 2) && (in_sizes[1] == 4 * NREGCH * 64 * 64);
  for (int l = 0; l < NLEV; ++l) {
    if (dict_order) {
      cls[l] = (const float*)d_in[3 * l + 0];
      reg[l] = (const float*)d_in[3 * l + 1];
      anc[l] = (const float*)d_in[3 * l + 2];
    } else {
      cls[l] = (const float*)d_in[l];
      reg[l] = (const float*)d_in[NLEV + l];
      anc[l] = (const float*)d_in[2 * NLEV + l];
    }
  }

  char* ws = (char*)d_ws;
  size_t off = 0;
  auto alloc = [&](size_t bytes) -> void* {
    void* p = ws + off;
    off = (off + bytes + 255) & ~(size_t)255;
    return p;
  };
  u32*    ctrs     = (u32*)   alloc(24 * 4);   // [0,20): selcnt, [20,24): invCnt
  u64*    sel      = (u64*)   alloc(20ULL * CAP * 8);
  float*  cand_s   = (float*) alloc((size_t)NB * NCAND * 4);
  u32*    cand_t   = (u32*)   alloc((size_t)NB * NCAND * 4);
  float4* cand_box = (float4*)alloc((size_t)NB * NCAND * 16);
  float4* rboxOff  = (float4*)alloc((size_t)NB * NCAND * 16);
  u32*    rmeta    = (u32*)   alloc((size_t)NB * NCAND * 4);
  u64*    rowsG    = (u64*)   alloc((size_t)NB * DCH * DW * 8);
  (void)ws_size; (void)out_size;

  u32* selcnt = ctrs;
  u32* invCnt = ctrs + 20;
  hipMemsetAsync(ctrs, 0, 24 * 4, stream);

  ClsPtrs cp;
  for (int l = 0; l < NLEV; ++l) cp.p[l] = cls[l];
  LevelPtrs lp;
  for (int l = 0; l < NLEV; ++l) { lp.reg[l] = reg[l]; lp.anc[l] = anc[l]; }

  k_filter<<<NB * NCHUNK_IMG, 256, 0, stream>>>(cp, selcnt, sel);
  k_rank<<<NB * NLEV, 1024, 0, stream>>>(cp, lp, selcnt, sel, cand_s, cand_t, cand_box);
  k_grank<<<dim3(NLEV, NB), 1024, 0, stream>>>(cand_s, cand_t, cand_box, invCnt, rboxOff, rmeta);
  k_mask<<<dim3(DW, NB), 256, 0, stream>>>(rboxOff, rowsG);
  k_detect<<<NB, 1024, 0, stream>>>(cand_s, cand_box, rboxOff, rmeta, rowsG, (float*)d_out);
}